// Round 11
// baseline (108.651 us; speedup 1.0000x reference)
//
#include <hip/hip_runtime.h>
#include <cfloat>

#define K_CODES 256
#define D_DIM 5
#define T_DIM 16384
#define B_DIM 32
#define NPTS (B_DIM * T_DIM)       // 524288 points
#define NELEM (NPTS * D_DIM)       // 2621440 elements
#define BLK 256
#define PTS_PER_BLK 512            // 128 quads, scanned by both k-halves
#define NBLOCKS (NPTS / PTS_PER_BLK)  // 1024 blocks: 4/CU, 4 waves/SIMD
#define POISON 0xAAAAAAAAu         // harness re-poisons d_ws to 0xAA bytes

__global__ __launch_bounds__(BLK, 4) void vq_fused(const float* __restrict__ x,
                                                   const float* __restrict__ e,
                                                   float* __restrict__ out,
                                                   double* __restrict__ partials,
                                                   unsigned int* __restrict__ cnt) {
    __shared__ float4 cbA[K_CODES];                 // c0..c3
    __shared__ __align__(16) float2 cbB[K_CODES];   // c4, esq
    __shared__ float mB[2 * PTS_PER_BLK];           // per-half best dist
    __shared__ int   mI[2 * PTS_PER_BLK];           // per-half best idx
    __shared__ float wsum[BLK / 64];
    __shared__ double dred[BLK / 64];
    __shared__ unsigned int doneFlag;

    const int tid = threadIdx.x;

    // ---- codebook prep into LDS (np-exact esq: rounded squares, seq adds) ----
    {
        int k = tid;  // BLK == K_CODES
        float v0 = e[0 * K_CODES + k];
        float v1 = e[1 * K_CODES + k];
        float v2 = e[2 * K_CODES + k];
        float v3 = e[3 * K_CODES + k];
        float v4 = e[4 * K_CODES + k];
        float esq = __fmul_rn(v0, v0);
        esq = __fadd_rn(esq, __fmul_rn(v1, v1));
        esq = __fadd_rn(esq, __fmul_rn(v2, v2));
        esq = __fadd_rn(esq, __fmul_rn(v3, v3));
        esq = __fadd_rn(esq, __fmul_rn(v4, v4));
        cbA[k] = make_float4(v0, v1, v2, v3);
        cbB[k] = make_float2(v4, esq);
    }
    __syncthreads();

    // ---- thread -> (point-quad, k-half) mapping ----
    const int qq = tid & 127;          // quad 0..127 within block
    const int h  = tid >> 7;           // 0: waves 0-1 (k 0..127); 1: waves 2-3
    const int hbase = h << 7;
    const int p0 = blockIdx.x * PTS_PER_BLK + qq * 4;
    const int b = p0 >> 14;            // 512 | 16384, no b straddle
    const int t = p0 & (T_DIM - 1);
    const float* xp = x + (b * D_DIM) * T_DIM + t;

    float xv[4][D_DIM];
    float xsq[4];
    float best[4];
    int bidx[4];

    #pragma unroll
    for (int d = 0; d < D_DIM; d++) {
        float4 v = *(const float4*)(xp + d * T_DIM);  // halves share -> L1 hit
        xv[0][d] = v.x; xv[1][d] = v.y; xv[2][d] = v.z; xv[3][d] = v.w;
    }
    // np: x**2 rounds each square, then sequential ascending adds (no fma)
    #pragma unroll
    for (int i = 0; i < 4; i++) {
        float s = __fmul_rn(xv[i][0], xv[i][0]);
        s = __fadd_rn(s, __fmul_rn(xv[i][1], xv[i][1]));
        s = __fadd_rn(s, __fmul_rn(xv[i][2], xv[i][2]));
        s = __fadd_rn(s, __fmul_rn(xv[i][3], xv[i][3]));
        s = __fadd_rn(s, __fmul_rn(xv[i][4], xv[i][4]));
        xsq[i] = s;
        best[i] = FLT_MAX;
        bidx[i] = hbase;
    }

    // ---- half-codebook scan: dot = rnd-mul + 4 RN-fma (sgemm chain);
    // dist = fma(-2,dot,xsq)+esq  ==bitwise==  (xsq-(dot+dot))+esq since
    // 2*dot is exact. strict < + ascending k = np first-min tie-break.
    // k is wave-uniform -> LDS broadcast, conflict-free.
    #pragma unroll 4
    for (int j = 0; j < 128; j += 2) {
        int k0 = hbase + j;
        float4 cA0 = cbA[k0];
        float4 cA1 = cbA[k0 + 1];
        float4 cBp = *(const float4*)&cbB[k0];  // (c4_k, esq_k, c4_k1, esq_k1)
        #pragma unroll
        for (int kk = 0; kk < 2; kk++) {
            float4 cA = kk ? cA1 : cA0;
            float c4 = kk ? cBp.z : cBp.x;
            float es = kk ? cBp.w : cBp.y;
            int ki = k0 + kk;
            #pragma unroll
            for (int i = 0; i < 4; i++) {
                float dot = __fmul_rn(xv[i][0], cA.x);
                dot = __fmaf_rn(xv[i][1], cA.y, dot);
                dot = __fmaf_rn(xv[i][2], cA.z, dot);
                dot = __fmaf_rn(xv[i][3], cA.w, dot);
                dot = __fmaf_rn(xv[i][4], c4, dot);
                float dist = __fadd_rn(__fmaf_rn(-2.0f, dot, xsq[i]), es);
                if (dist < best[i]) { best[i] = dist; bidx[i] = ki; }
            }
        }
    }

    // ---- publish half-results, merge, epilogue (2 points per thread) ----
    #pragma unroll
    for (int i = 0; i < 4; i++) {
        mB[h * PTS_PER_BLK + qq * 4 + i] = best[i];
        mI[h * PTS_PER_BLK + qq * 4 + i] = bidx[i];
    }
    __syncthreads();

    const int lp = tid * 2;                      // block-local points lp, lp+1
    const int pp = blockIdx.x * PTS_PER_BLK + lp;
    const int bb = pp >> 14;
    const int tt = pp & (T_DIM - 1);
    const float* xq = x + (bb * D_DIM) * T_DIM + tt;
    float* op = out + (bb * D_DIM) * T_DIM + tt;

    float ls = 0.f;
    float2 ov[D_DIM];
    #pragma unroll
    for (int j2 = 0; j2 < 2; j2++) {
        int j = lp + j2;
        float bl = mB[j];
        int il = mI[j];
        float bh = mB[PTS_PER_BLK + j];
        int ih = mI[PTS_PER_BLK + j];
        int win = (bh < bl) ? ih : il;   // strict <: low half (smaller k) wins ties
        float4 gA = cbA[win];
        float2 gB = cbB[win];
        float q[D_DIM] = {gA.x, gA.y, gA.z, gA.w, gB.x};
        #pragma unroll
        for (int d = 0; d < D_DIM; d++) {
            float xs = xq[d * T_DIM + j2];        // L1/L2-hot re-read
            float df = xs - q[d];
            ls += df * df;
            (j2 ? ov[d].y : ov[d].x) = q[d];
        }
    }
    #pragma unroll
    for (int d = 0; d < D_DIM; d++)
        *(float2*)(op + d * T_DIM) = ov[d];       // coalesced 8 B/lane

    // ---- block loss partial -> global slot (overwritten every launch) ----
    #pragma unroll
    for (int off = 32; off > 0; off >>= 1) ls += __shfl_down(ls, off, 64);
    int lane = tid & 63;
    int wid = tid >> 6;
    if (lane == 0) wsum[wid] = ls;
    __syncthreads();
    if (tid == 0) {
        float tot = 0.f;
        #pragma unroll
        for (int w = 0; w < BLK / 64; w++) tot += wsum[w];
        partials[blockIdx.x] = (double)tot;
        __threadfence();
        unsigned int old = atomicAdd(cnt, 1u);
        // replay-robust: counter starts at POISON each poisoned launch; pure
        // modulo also works if poison is not refreshed between graph replays.
        doneFlag = (((old - POISON) & (NBLOCKS - 1)) == (NBLOCKS - 1)) ? 1u : 0u;
    }
    __syncthreads();

    // ---- last block finalizes the losses ----
    if (doneFlag) {
        __threadfence();
        double v = partials[tid] + partials[tid + 256] + partials[tid + 512] +
                   partials[tid + 768];
        #pragma unroll
        for (int off = 32; off > 0; off >>= 1) v += __shfl_down(v, off, 64);
        if (lane == 0) dred[wid] = v;
        __syncthreads();
        if (tid == 0) {
            double tot = dred[0] + dred[1] + dred[2] + dred[3];
            float loss = (float)(tot / (double)NELEM);
            out[NELEM] = loss;      // dictionary_loss
            out[NELEM + 1] = loss;  // commitment_loss (identical forward value)
        }
    }
}

extern "C" void kernel_launch(void* const* d_in, const int* in_sizes, int n_in,
                              void* d_out, int out_size, void* d_ws, size_t ws_size,
                              hipStream_t stream) {
    const float* x = (const float*)d_in[0];   // fp32 (B,D,T)
    const float* e = (const float*)d_in[1];   // fp32 (D,K)
    float* out = (float*)d_out;               // fp32: quantized + 2 losses
    double* partials = (double*)d_ws;                         // 8 KB
    unsigned int* cnt = (unsigned int*)((char*)d_ws + 8192);  // poisoned 0xAA..

    vq_fused<<<NBLOCKS, BLK, 0, stream>>>(x, e, out, partials, cnt);
}

// Round 12
// 105.425 us; speedup vs baseline: 1.0306x; 1.0306x over previous
//
#include <hip/hip_runtime.h>
#include <cfloat>

#define K_CODES 256
#define D_DIM 5
#define T_DIM 16384
#define B_DIM 32
#define NPTS (B_DIM * T_DIM)       // 524288 points
#define NELEM (NPTS * D_DIM)       // 2621440 elements
#define BLK 256
#define PTS_PER_BLK 1024           // 128 octets, scanned by both k-halves
#define NBLOCKS (NPTS / PTS_PER_BLK)  // 512 blocks: 2/CU, 2 waves/SIMD
#define POISON 0xAAAAAAAAu         // harness re-poisons d_ws to 0xAA bytes

__global__ __launch_bounds__(BLK, 2) void vq_fused(const float* __restrict__ x,
                                                   const float* __restrict__ e,
                                                   float* __restrict__ out,
                                                   double* __restrict__ partials,
                                                   unsigned int* __restrict__ cnt) {
    __shared__ float4 cbA[K_CODES];                   // c0..c3   (4 KB)
    __shared__ __align__(16) float2 cbB[K_CODES];     // c4, esq  (2 KB)
    __shared__ __align__(16) float mB[2 * PTS_PER_BLK];  // 8 KB best dist
    __shared__ __align__(16) int   mI[2 * PTS_PER_BLK];  // 8 KB best idx
    __shared__ float wsum[BLK / 64];
    __shared__ double dred[BLK / 64];
    __shared__ unsigned int doneFlag;

    const int tid = threadIdx.x;

    // ---- codebook prep into LDS (np-exact esq: rounded squares, seq adds) ----
    {
        int k = tid;  // BLK == K_CODES
        float v0 = e[0 * K_CODES + k];
        float v1 = e[1 * K_CODES + k];
        float v2 = e[2 * K_CODES + k];
        float v3 = e[3 * K_CODES + k];
        float v4 = e[4 * K_CODES + k];
        float esq = __fmul_rn(v0, v0);
        esq = __fadd_rn(esq, __fmul_rn(v1, v1));
        esq = __fadd_rn(esq, __fmul_rn(v2, v2));
        esq = __fadd_rn(esq, __fmul_rn(v3, v3));
        esq = __fadd_rn(esq, __fmul_rn(v4, v4));
        cbA[k] = make_float4(v0, v1, v2, v3);
        cbB[k] = make_float2(v4, esq);
    }
    __syncthreads();

    // ---- thread -> (point-octet, k-half) mapping: 8 pts/thread ----
    const int q8 = tid & 127;          // octet 0..127
    const int h  = tid >> 7;           // 0: k in [0,128); 1: k in [128,256)
    const int hbase = h << 7;
    const int p0 = blockIdx.x * PTS_PER_BLK + q8 * 8;
    const int b = p0 >> 14;            // 1024 | 16384, no b straddle
    const int t = p0 & (T_DIM - 1);
    const float* xp = x + (b * D_DIM) * T_DIM + t;

    float xv[8][D_DIM];
    float xsq[8];
    float best[8];
    int bidx[8];

    #pragma unroll
    for (int d = 0; d < D_DIM; d++) {
        float4 va = *(const float4*)(xp + d * T_DIM);      // halves share -> L1
        float4 vb = *(const float4*)(xp + d * T_DIM + 4);
        xv[0][d] = va.x; xv[1][d] = va.y; xv[2][d] = va.z; xv[3][d] = va.w;
        xv[4][d] = vb.x; xv[5][d] = vb.y; xv[6][d] = vb.z; xv[7][d] = vb.w;
    }
    // np: x**2 rounds each square, then sequential ascending adds (no fma)
    #pragma unroll
    for (int i = 0; i < 8; i++) {
        float s = __fmul_rn(xv[i][0], xv[i][0]);
        s = __fadd_rn(s, __fmul_rn(xv[i][1], xv[i][1]));
        s = __fadd_rn(s, __fmul_rn(xv[i][2], xv[i][2]));
        s = __fadd_rn(s, __fmul_rn(xv[i][3], xv[i][3]));
        s = __fadd_rn(s, __fmul_rn(xv[i][4], xv[i][4]));
        xsq[i] = s;
        best[i] = FLT_MAX;
        bidx[i] = hbase;
    }

    // ---- half-codebook scan: dot = rnd-mul + 4 RN-fma (sgemm chain);
    // dist = fma(-2,dot,xsq)+esq == bitwise == (xsq-(dot+dot))+esq (2*dot
    // exact). strict < + ascending k = np first-min. k wave-uniform -> LDS
    // broadcast, conflict-free. 8 pts/thread: VALU 320 cyc per k-pair vs
    // LDS 36 cyc -> VALU-bound (decoupled).
    #pragma unroll 2
    for (int j = 0; j < 128; j += 2) {
        int k0 = hbase + j;
        float4 cA0 = cbA[k0];
        float4 cA1 = cbA[k0 + 1];
        float4 cBp = *(const float4*)&cbB[k0];  // (c4_k, esq_k, c4_k1, esq_k1)
        #pragma unroll
        for (int kk = 0; kk < 2; kk++) {
            float4 cA = kk ? cA1 : cA0;
            float c4 = kk ? cBp.z : cBp.x;
            float es = kk ? cBp.w : cBp.y;
            int ki = k0 + kk;
            #pragma unroll
            for (int i = 0; i < 8; i++) {
                float dot = __fmul_rn(xv[i][0], cA.x);
                dot = __fmaf_rn(xv[i][1], cA.y, dot);
                dot = __fmaf_rn(xv[i][2], cA.z, dot);
                dot = __fmaf_rn(xv[i][3], cA.w, dot);
                dot = __fmaf_rn(xv[i][4], c4, dot);
                float dist = __fadd_rn(__fmaf_rn(-2.0f, dot, xsq[i]), es);
                if (dist < best[i]) { best[i] = dist; bidx[i] = ki; }
            }
        }
    }

    // ---- publish half-results (vector LDS writes), merge, epilogue ----
    #pragma unroll
    for (int i = 0; i < 8; i += 4) {
        *(float4*)&mB[h * PTS_PER_BLK + q8 * 8 + i] =
            make_float4(best[i], best[i + 1], best[i + 2], best[i + 3]);
        *(int4*)&mI[h * PTS_PER_BLK + q8 * 8 + i] =
            make_int4(bidx[i], bidx[i + 1], bidx[i + 2], bidx[i + 3]);
    }
    __syncthreads();

    // each thread finalizes 4 consecutive points
    const int lp = tid * 4;
    const int pp = blockIdx.x * PTS_PER_BLK + lp;
    const int bb = pp >> 14;
    const int tt = pp & (T_DIM - 1);
    const float* xq = x + (bb * D_DIM) * T_DIM + tt;
    float* op = out + (bb * D_DIM) * T_DIM + tt;

    float4 bl4 = *(const float4*)&mB[lp];
    int4   il4 = *(const int4*)&mI[lp];
    float4 bh4 = *(const float4*)&mB[PTS_PER_BLK + lp];
    int4   ih4 = *(const int4*)&mI[PTS_PER_BLK + lp];
    int win[4];
    win[0] = (bh4.x < bl4.x) ? ih4.x : il4.x;  // strict <: low half wins ties
    win[1] = (bh4.y < bl4.y) ? ih4.y : il4.y;
    win[2] = (bh4.z < bl4.z) ? ih4.z : il4.z;
    win[3] = (bh4.w < bl4.w) ? ih4.w : il4.w;

    float ls = 0.f;
    float ov[D_DIM][4];
    #pragma unroll
    for (int j2 = 0; j2 < 4; j2++) {
        float4 gA = cbA[win[j2]];
        float2 gB = cbB[win[j2]];
        float qv[D_DIM] = {gA.x, gA.y, gA.z, gA.w, gB.x};
        #pragma unroll
        for (int d = 0; d < D_DIM; d++) {
            float xs = xq[d * T_DIM + j2];        // L1-hot re-read
            float df = xs - qv[d];
            ls += df * df;
            ov[d][j2] = qv[d];
        }
    }
    #pragma unroll
    for (int d = 0; d < D_DIM; d++)
        *(float4*)(op + d * T_DIM) =
            make_float4(ov[d][0], ov[d][1], ov[d][2], ov[d][3]);  // coalesced

    // ---- block loss partial -> global slot (overwritten every launch) ----
    #pragma unroll
    for (int off = 32; off > 0; off >>= 1) ls += __shfl_down(ls, off, 64);
    int lane = tid & 63;
    int wid = tid >> 6;
    if (lane == 0) wsum[wid] = ls;
    __syncthreads();
    if (tid == 0) {
        float tot = 0.f;
        #pragma unroll
        for (int w = 0; w < BLK / 64; w++) tot += wsum[w];
        partials[blockIdx.x] = (double)tot;
        __threadfence();
        unsigned int old = atomicAdd(cnt, 1u);
        // launch-count-invariant: each launch adds exactly NBLOCKS
        doneFlag = (((old - POISON) & (NBLOCKS - 1)) == (NBLOCKS - 1)) ? 1u : 0u;
    }
    __syncthreads();

    // ---- last block finalizes the losses ----
    if (doneFlag) {
        __threadfence();
        double v = partials[tid] + partials[tid + 256];
        #pragma unroll
        for (int off = 32; off > 0; off >>= 1) v += __shfl_down(v, off, 64);
        if (lane == 0) dred[wid] = v;
        __syncthreads();
        if (tid == 0) {
            double tot = dred[0] + dred[1] + dred[2] + dred[3];
            float loss = (float)(tot / (double)NELEM);
            out[NELEM] = loss;      // dictionary_loss
            out[NELEM + 1] = loss;  // commitment_loss (identical forward value)
        }
    }
}

extern "C" void kernel_launch(void* const* d_in, const int* in_sizes, int n_in,
                              void* d_out, int out_size, void* d_ws, size_t ws_size,
                              hipStream_t stream) {
    const float* x = (const float*)d_in[0];   // fp32 (B,D,T)
    const float* e = (const float*)d_in[1];   // fp32 (D,K)
    float* out = (float*)d_out;               // fp32: quantized + 2 losses
    double* partials = (double*)d_ws;                         // 4 KB
    unsigned int* cnt = (unsigned int*)((char*)d_ws + 8192);  // poisoned 0xAA..

    vq_fused<<<NBLOCKS, BLK, 0, stream>>>(x, e, out, partials, cnt);
}